// Round 2
// baseline (441.035 us; speedup 1.0000x reference)
//
#include <hip/hip_runtime.h>

// Haar DWT level-1.
// Input:  (16, 1, 2048, 2048) fp32
// Output: low  (16, 1, 1024, 1024) fp32  — LL
//         high (16, 3, 1024, 1024) fp32  — LH, HL, HH
// d_out = [low | high] flat.
//
// Each thread: 4 output pixels. Reads 2x float4 from each of two input
// rows (32 B/lane/row, coalesced), writes one 16B vector (ext_vector_type
// so __builtin_nontemporal_store accepts it) to each of the 4 subband
// planes. Non-temporal: pure streaming, no reuse — keep the 256 MiB L3
// from thrashing on 512 MiB of traffic.

#define B   16
#define H   2048
#define W   2048
#define HO  1024
#define WO  1024

typedef float v4f __attribute__((ext_vector_type(4)));

__global__ __launch_bounds__(256) void dwt_haar_kernel(
    const float* __restrict__ x, float* __restrict__ out)
{
    // total threads = B * HO * (WO/4) = 16 * 1024 * 256 = 4,194,304
    const unsigned tid = blockIdx.x * blockDim.x + threadIdx.x;
    const int j4 = tid & 255;          // v4 column index [0,256)
    const int i  = (tid >> 8) & 1023;  // output row
    const int b  = tid >> 18;          // batch

    const size_t in_base = (size_t)b * H * W + (size_t)(2 * i) * W + 8 * (size_t)j4;

    // row 0: a0 b0 a1 b1 | a2 b2 a3 b3
    const v4f r0lo = *(const v4f*)(x + in_base);
    const v4f r0hi = *(const v4f*)(x + in_base + 4);
    // row 1: c0 d0 c1 d1 | c2 d2 c3 d3
    const v4f r1lo = *(const v4f*)(x + in_base + W);
    const v4f r1hi = *(const v4f*)(x + in_base + W + 4);

    const float a0 = r0lo.x, b0 = r0lo.y, a1 = r0lo.z, b1 = r0lo.w;
    const float a2 = r0hi.x, b2 = r0hi.y, a3 = r0hi.z, b3 = r0hi.w;
    const float c0 = r1lo.x, d0 = r1lo.y, c1 = r1lo.z, d1 = r1lo.w;
    const float c2 = r1hi.x, d2 = r1hi.y, c3 = r1hi.z, d3 = r1hi.w;

    v4f LL, LH, HL, HH;
    LL.x = (a0 + b0 + c0 + d0) * 0.5f;  LL.y = (a1 + b1 + c1 + d1) * 0.5f;
    LL.z = (a2 + b2 + c2 + d2) * 0.5f;  LL.w = (a3 + b3 + c3 + d3) * 0.5f;
    LH.x = (a0 + b0 - c0 - d0) * 0.5f;  LH.y = (a1 + b1 - c1 - d1) * 0.5f;
    LH.z = (a2 + b2 - c2 - d2) * 0.5f;  LH.w = (a3 + b3 - c3 - d3) * 0.5f;
    HL.x = (a0 - b0 + c0 - d0) * 0.5f;  HL.y = (a1 - b1 + c1 - d1) * 0.5f;
    HL.z = (a2 - b2 + c2 - d2) * 0.5f;  HL.w = (a3 - b3 + c3 - d3) * 0.5f;
    HH.x = (a0 - b0 - c0 + d0) * 0.5f;  HH.y = (a1 - b1 - c1 + d1) * 0.5f;
    HH.z = (a2 - b2 - c2 + d2) * 0.5f;  HH.w = (a3 - b3 - c3 + d3) * 0.5f;

    const size_t plane  = (size_t)HO * WO;          // 1,048,576
    const size_t row_off = (size_t)i * WO;

    float* low  = out;                              // (B,1,HO,WO)
    float* high = out + (size_t)B * plane;          // (B,3,HO,WO)

    v4f* pLL = (v4f*)(low  + (size_t)b * plane           + row_off) + j4;
    v4f* pLH = (v4f*)(high + (size_t)(b * 3 + 0) * plane + row_off) + j4;
    v4f* pHL = (v4f*)(high + (size_t)(b * 3 + 1) * plane + row_off) + j4;
    v4f* pHH = (v4f*)(high + (size_t)(b * 3 + 2) * plane + row_off) + j4;

    __builtin_nontemporal_store(LL, pLL);
    __builtin_nontemporal_store(LH, pLH);
    __builtin_nontemporal_store(HL, pHL);
    __builtin_nontemporal_store(HH, pHH);
}

extern "C" void kernel_launch(void* const* d_in, const int* in_sizes, int n_in,
                              void* d_out, int out_size, void* d_ws, size_t ws_size,
                              hipStream_t stream) {
    const float* x = (const float*)d_in[0];
    float* out = (float*)d_out;

    const int total_threads = B * HO * (WO / 4);   // 4,194,304
    const int block = 256;
    const int grid = total_threads / block;        // 16,384

    dwt_haar_kernel<<<grid, block, 0, stream>>>(x, out);
}

// Round 3
// 439.435 us; speedup vs baseline: 1.0036x; 1.0036x over previous
//
#include <hip/hip_runtime.h>

// Haar DWT level-1.
// Input:  (16, 1, 2048, 2048) fp32
// Output: low  (16, 1, 1024, 1024) fp32  — LL
//         high (16, 3, 1024, 1024) fp32  — LH, HL, HH
// d_out = [low | high] flat.
//
// Round-0 structure (known-good 428.7 µs): each thread computes 2 output
// pixels. One float4 load per input row (16 B/lane, lanes at 16 B stride
// -> perfectly packed 1 KiB/instruction), two rows; one float2 store per
// subband (8 B/lane, fully coalesced 512 B/instruction).
// Round-2 lesson: widening to 4 px/thread put lanes at 32 B stride on
// loads (half of every cacheline per instruction, 2x read requests) and
// regressed ~12 µs. Reverted.
// This round's single delta: non-temporal stores (ext_vector_type so the
// builtin accepts them) — pure streaming, zero reuse, 512 MiB traffic vs
// 256 MiB L3; mark output lines evict-first.

#define B   16
#define H   2048
#define W   2048
#define HO  1024
#define WO  1024

typedef float v2f __attribute__((ext_vector_type(2)));

__global__ __launch_bounds__(256) void dwt_haar_kernel(
    const float* __restrict__ x, float* __restrict__ out)
{
    // total threads = B * HO * (WO/2) = 16 * 1024 * 512 = 8,388,608
    const unsigned tid = blockIdx.x * blockDim.x + threadIdx.x;
    const int j2 = tid & 511;          // float2 column index [0,512)
    const int i  = (tid >> 9) & 1023;  // output row
    const int b  = tid >> 19;          // batch

    const size_t in_base = (size_t)b * H * W + (size_t)(2 * i) * W + 4 * (size_t)j2;
    const float4 r0 = *(const float4*)(x + in_base);        // a0 b0 a1 b1
    const float4 r1 = *(const float4*)(x + in_base + W);    // c0 d0 c1 d1

    const float a0 = r0.x, b0 = r0.y, a1 = r0.z, b1 = r0.w;
    const float c0 = r1.x, d0 = r1.y, c1 = r1.z, d1 = r1.w;

    v2f LL, LH, HL, HH;
    LL.x = (a0 + b0 + c0 + d0) * 0.5f;  LL.y = (a1 + b1 + c1 + d1) * 0.5f;
    LH.x = (a0 + b0 - c0 - d0) * 0.5f;  LH.y = (a1 + b1 - c1 - d1) * 0.5f;
    HL.x = (a0 - b0 + c0 - d0) * 0.5f;  HL.y = (a1 - b1 + c1 - d1) * 0.5f;
    HH.x = (a0 - b0 - c0 + d0) * 0.5f;  HH.y = (a1 - b1 - c1 + d1) * 0.5f;

    const size_t plane   = (size_t)HO * WO;        // 1,048,576
    const size_t row_off = (size_t)i * WO;

    float* low  = out;                              // (B,1,HO,WO)
    float* high = out + (size_t)B * plane;          // (B,3,HO,WO)

    v2f* pLL = (v2f*)(low  + (size_t)b * plane           + row_off) + j2;
    v2f* pLH = (v2f*)(high + (size_t)(b * 3 + 0) * plane + row_off) + j2;
    v2f* pHL = (v2f*)(high + (size_t)(b * 3 + 1) * plane + row_off) + j2;
    v2f* pHH = (v2f*)(high + (size_t)(b * 3 + 2) * plane + row_off) + j2;

    __builtin_nontemporal_store(LL, pLL);
    __builtin_nontemporal_store(LH, pLH);
    __builtin_nontemporal_store(HL, pHL);
    __builtin_nontemporal_store(HH, pHH);
}

extern "C" void kernel_launch(void* const* d_in, const int* in_sizes, int n_in,
                              void* d_out, int out_size, void* d_ws, size_t ws_size,
                              hipStream_t stream) {
    const float* x = (const float*)d_in[0];
    float* out = (float*)d_out;

    const int total_threads = B * HO * (WO / 2);   // 8,388,608
    const int block = 256;
    const int grid = total_threads / block;        // 32,768

    dwt_haar_kernel<<<grid, block, 0, stream>>>(x, out);
}

// Round 4
// 427.615 us; speedup vs baseline: 1.0314x; 1.0276x over previous
//
#include <hip/hip_runtime.h>

// Haar DWT level-1 — FINAL (round-0 known-best structure, 428.7 µs bench).
// Input:  (16, 1, 2048, 2048) fp32
// Output: low  (16, 1, 1024, 1024) fp32  — LL
//         high (16, 3, 1024, 1024) fp32  — LH, HL, HH
// d_out = [low | high] flat.
//
// Each thread: 2 output pixels. One float4 load per input row (16 B/lane,
// lanes at 16 B stride -> perfectly packed 1 KiB/instruction), two rows;
// one float2 store per subband (8 B/lane, fully coalesced).
//
// Measured ablations (this session):
//  - 4 px/thread (32 B-stride loads): +12 µs — half-cacheline loads double
//    read requests. REJECTED.
//  - __builtin_nontemporal_store: +10 µs or neutral (within fill noise;
//    never a win). REJECTED.
// Kernel is ~95 µs for 537 MB moved = ~5.6 TB/s mixed-stream ≈ roofline.

#define B   16
#define H   2048
#define W   2048
#define HO  1024
#define WO  1024

__global__ __launch_bounds__(256) void dwt_haar_kernel(
    const float* __restrict__ x, float* __restrict__ out)
{
    // total threads = B * HO * (WO/2) = 16 * 1024 * 512 = 8,388,608
    const unsigned tid = blockIdx.x * blockDim.x + threadIdx.x;
    const int j2 = tid & 511;          // float2 column index [0,512)
    const int i  = (tid >> 9) & 1023;  // output row
    const int b  = tid >> 19;          // batch

    const size_t in_base = (size_t)b * H * W + (size_t)(2 * i) * W + 4 * (size_t)j2;
    const float4 r0 = *(const float4*)(x + in_base);        // a0 b0 a1 b1
    const float4 r1 = *(const float4*)(x + in_base + W);    // c0 d0 c1 d1

    const float a0 = r0.x, b0 = r0.y, a1 = r0.z, b1 = r0.w;
    const float c0 = r1.x, d0 = r1.y, c1 = r1.z, d1 = r1.w;

    const float2 LL = make_float2((a0 + b0 + c0 + d0) * 0.5f,
                                  (a1 + b1 + c1 + d1) * 0.5f);
    const float2 LH = make_float2((a0 + b0 - c0 - d0) * 0.5f,
                                  (a1 + b1 - c1 - d1) * 0.5f);
    const float2 HL = make_float2((a0 - b0 + c0 - d0) * 0.5f,
                                  (a1 - b1 + c1 - d1) * 0.5f);
    const float2 HH = make_float2((a0 - b0 - c0 + d0) * 0.5f,
                                  (a1 - b1 - c1 + d1) * 0.5f);

    const size_t plane   = (size_t)HO * WO;        // 1,048,576
    const size_t row_off = (size_t)i * WO;

    float* low  = out;                              // (B,1,HO,WO)
    float* high = out + (size_t)B * plane;          // (B,3,HO,WO)

    ((float2*)(low  + (size_t)b * plane           + row_off))[j2] = LL;
    ((float2*)(high + (size_t)(b * 3 + 0) * plane + row_off))[j2] = LH;
    ((float2*)(high + (size_t)(b * 3 + 1) * plane + row_off))[j2] = HL;
    ((float2*)(high + (size_t)(b * 3 + 2) * plane + row_off))[j2] = HH;
}

extern "C" void kernel_launch(void* const* d_in, const int* in_sizes, int n_in,
                              void* d_out, int out_size, void* d_ws, size_t ws_size,
                              hipStream_t stream) {
    const float* x = (const float*)d_in[0];
    float* out = (float*)d_out;

    const int total_threads = B * HO * (WO / 2);   // 8,388,608
    const int block = 256;
    const int grid = total_threads / block;        // 32,768

    dwt_haar_kernel<<<grid, block, 0, stream>>>(x, out);
}